// Round 4
// baseline (329.817 us; speedup 1.0000x reference)
//
#include <hip/hip_runtime.h>
#include <math.h>

namespace {
constexpr int Bn = 8, Cn = 3, Hn = 512, Wn = 960;
constexpr int RS = 8;               // output rows per tile
constexpr int SR = RS + 2;          // staged rows (tile + halo)
constexpr int CW = 256;             // columns per tile
constexpr int SC = CW + 2;          // staged cols (tile + halo)
constexpr int TPB = 256;            // 4 waves
constexpr int NBX = (Wn + CW - 1) / CW;   // 4
constexpr int NSTRIP = Hn / RS;           // 64
constexpr int NBLK = NBX * NSTRIP * Bn;   // 2048
constexpr float kC1 = 1e-4f;        // 0.01^2
constexpr float kC2 = 9e-4f;        // 0.03^2
constexpr float kEps2 = 1e-6f;      // 0.001^2
}

__global__ __launch_bounds__(TPB) void stereo_fused(
    const float* __restrict__ left, const float* __restrict__ right,
    const float* __restrict__ d_left, const float* __restrict__ d_right,
    const float* __restrict__ nonocc, float* __restrict__ acc,
    float* __restrict__ out)
{
    __shared__ float sW[SR][SC];        // warped right, one channel at a time
    __shared__ float red[3][TPB / 64];

    const int t = threadIdx.x;          // 0..255
    const int bx = blockIdx.x;
    const int strip = blockIdx.y;
    const int b = blockIdx.z;
    const int y0 = strip * RS;
    const int x = bx * CW + t;          // global output column
    const bool inb = (x < Wn);
    const int xc = min(x, Wn - 1);      // address-safe column

    const float* leftB  = left   + (size_t)b * Cn * Hn * Wn;
    const float* rightB = right  + (size_t)b * Cn * Hn * Wn;
    const float* dL = d_left  + (size_t)b * Hn * Wn;
    const float* dR = d_right + (size_t)b * Hn * Wn;
    const float* no = nonocc  + (size_t)b * Hn * Wn;

    // ---- Phase A: per output row: valid weight + LR loss ----
    float vw_r[RS];
    float p_sum = 0.f, v_sum = 0.f, l_sum = 0.f;
    #pragma unroll
    for (int k = 0; k < RS; ++k) {
        int y = y0 + k;
        float d = dL[y * Wn + xc];
        float xs = (float)x - d;
        float gx = 2.f * xs / (float)(Wn - 1) - 1.f;
        float vmask = (inb && gx >= -1.f && gx <= 1.f) ? 1.f : 0.f;
        float vw = vmask * no[y * Wn + xc];
        vw_r[k] = vw;
        v_sum += vw;
        float x0f = floorf(xs);
        float wx = xs - x0f;
        int xi = (int)x0f;
        int x0i = min(max(xi, 0), Wn - 1);
        int x1i = min(max(xi + 1, 0), Wn - 1);
        const float* drow = dR + y * Wn;
        float drw = (1.f - wx) * drow[x0i] + wx * drow[x1i];
        float dd = d - drw;
        l_sum += sqrtf(dd * dd + kEps2) * vw;
    }

    const float xm_l = (x > 0) ? 1.f : 0.f;         // horizontal pad masks (global)
    const float xm_r = (x < Wn - 1) ? 1.f : 0.f;
    const int xl = max(x - 1, 0);                   // clamped neighbor addresses
    const int xr = min(x + 1, Wn - 1);
    const float inv_cx = (x == 0 || x == Wn - 1) ? 0.5f : (1.f / 3.f);
    const int g0 = bx * CW - 1;                     // global col of staged index 0

    #pragma unroll
    for (int c = 0; c < Cn; ++c) {
        __syncthreads();                // prior channel's reads done before overwrite
        // ---- stage warped right channel c into LDS [SR][SC] ----
        const float* rchan = rightB + (size_t)c * Hn * Wn;
        #pragma unroll
        for (int r = 0; r < SR; ++r) {
            int y = y0 - 1 + r;
            bool yok = (y >= 0 && y < Hn);          // wave-uniform
            // main staged element s = t  (global col g0 + t)
            {
                int g = g0 + t;
                float wv = 0.f;
                if (yok && g >= 0 && g < Wn) {
                    float xs = (float)g - dL[y * Wn + g];
                    float x0f = floorf(xs);
                    float wx = xs - x0f;
                    int xi = (int)x0f;
                    int x0i = min(max(xi, 0), Wn - 1);
                    int x1i = min(max(xi + 1, 0), Wn - 1);
                    const float* rrow = rchan + (size_t)y * Wn;
                    wv = (1.f - wx) * rrow[x0i] + wx * rrow[x1i];
                }
                sW[r][t] = wv;
            }
            // halo staged elements s = CW + t for t in {0,1}
            if (t < 2) {
                int g = g0 + CW + t;
                float wv = 0.f;
                if (yok && g >= 0 && g < Wn) {
                    float xs = (float)g - dL[y * Wn + g];
                    float x0f = floorf(xs);
                    float wx = xs - x0f;
                    int xi = (int)x0f;
                    int x0i = min(max(xi, 0), Wn - 1);
                    int x1i = min(max(xi + 1, 0), Wn - 1);
                    const float* rrow = rchan + (size_t)y * Wn;
                    wv = (1.f - wx) * rrow[x0i] + wx * rrow[x1i];
                }
                sW[r][CW + t] = wv;
            }
        }
        __syncthreads();

        // ---- vertical ring: 3 rows x 3 taps of left (L1) + warped (LDS) ----
        const float* lchan = leftB + (size_t)c * Hn * Wn;
        float lA[3][3], wA[3][3];
        #pragma unroll
        for (int r = 0; r < 2; ++r) {
            int y = y0 - 1 + r;
            int yy = min(max(y, 0), Hn - 1);
            float ym = (y >= 0 && y < Hn) ? 1.f : 0.f;
            const float* lrow = lchan + (size_t)yy * Wn;
            lA[r][0] = lrow[xl] * (ym * xm_l);
            lA[r][1] = lrow[xc] * ym;
            lA[r][2] = lrow[xr] * (ym * xm_r);
            wA[r][0] = sW[r][t];
            wA[r][1] = sW[r][t + 1];
            wA[r][2] = sW[r][t + 2];
        }
        #pragma unroll
        for (int k = 0; k < RS; ++k) {
            const int rn = k + 2;
            const int sn = rn % 3;
            {
                int y = y0 - 1 + rn;
                int yy = min(max(y, 0), Hn - 1);
                float ym = (y >= 0 && y < Hn) ? 1.f : 0.f;
                const float* lrow = lchan + (size_t)yy * Wn;
                lA[sn][0] = lrow[xl] * (ym * xm_l);
                lA[sn][1] = lrow[xc] * ym;
                lA[sn][2] = lrow[xr] * (ym * xm_r);
                wA[sn][0] = sW[rn][t];
                wA[sn][1] = sW[rn][t + 1];
                wA[sn][2] = sW[rn][t + 2];
            }
            float Sx = 0.f, Sy = 0.f, Sxx = 0.f, Syy = 0.f, Sxy = 0.f;
            #pragma unroll
            for (int s = 0; s < 3; ++s)
                #pragma unroll
                for (int j = 0; j < 3; ++j) {
                    float l = lA[s][j], w = wA[s][j];
                    Sx += l; Sy += w;
                    Sxx = fmaf(l, l, Sxx);
                    Syy = fmaf(w, w, Syy);
                    Sxy = fmaf(l, w, Sxy);
                }
            int y = y0 + k;
            float inv_cy = (y == 0 || y == Hn - 1) ? 0.5f : (1.f / 3.f);
            float inv = inv_cy * inv_cx;
            float mu_x = Sx * inv, mu_y = Sy * inv;
            float sig_x  = Sxx * inv - mu_x * mu_x;
            float sig_y  = Syy * inv - mu_y * mu_y;
            float sig_xy = Sxy * inv - mu_x * mu_y;
            float num = (2.f * mu_x * mu_y + kC1) * (2.f * sig_xy + kC2);
            float den = (mu_x * mu_x + mu_y * mu_y + kC1) * (sig_x + sig_y + kC2);
            float ssim = num / (den + 1e-12f);
            float sm = fminf(fmaxf(0.5f * (1.f - ssim), 0.f), 1.f);
            float lc = lA[(k + 1) % 3][1], wc = wA[(k + 1) % 3][1];
            float df = lc - wc;
            float l1 = sqrtf(df * df + kEps2);
            p_sum += (0.28333333333f * sm + 0.05f * l1) * vw_r[k];  // alpha/3, (1-alpha)/3
        }
    }

    // ---- block reduction -> 3 global atomics -> ticketed finalize ----
    #pragma unroll
    for (int off = 32; off > 0; off >>= 1) {
        p_sum += __shfl_down(p_sum, off);
        v_sum += __shfl_down(v_sum, off);
        l_sum += __shfl_down(l_sum, off);
    }
    int lane = t & 63, wv = t >> 6;
    if (lane == 0) { red[0][wv] = p_sum; red[1][wv] = v_sum; red[2][wv] = l_sum; }
    __syncthreads();
    if (t == 0) {
        float P = 0.f, V = 0.f, L = 0.f;
        #pragma unroll
        for (int i = 0; i < TPB / 64; ++i) { P += red[0][i]; V += red[1][i]; L += red[2][i]; }
        atomicAdd(&acc[0], P);
        atomicAdd(&acc[1], V);
        atomicAdd(&acc[2], L);
        __threadfence();
        unsigned prev = atomicAdd((unsigned*)&acc[3], 1u);
        if (prev == NBLK - 1) {         // last block finalizes
            float Pa = atomicAdd(&acc[0], 0.f);
            float Va = atomicAdd(&acc[1], 0.f);
            float La = atomicAdd(&acc[2], 0.f);
            float photo = Pa / (Va + 1e-6f);
            float lr = La / (Va + 1e-6f);
            out[0] = photo + 0.2f * lr; // W_PHOTO=1, W_LR=0.2
            out[1] = photo;
            out[2] = lr;
            out[3] = Va * (1.f / (float)(Bn * Hn * Wn));
        }
    }
}

extern "C" void kernel_launch(void* const* d_in, const int* in_sizes, int n_in,
                              void* d_out, int out_size, void* d_ws, size_t ws_size,
                              hipStream_t stream) {
    const float* left   = (const float*)d_in[0];
    const float* right  = (const float*)d_in[1];
    const float* dl     = (const float*)d_in[2];
    const float* dr     = (const float*)d_in[3];
    const float* nonocc = (const float*)d_in[4];
    float* acc = (float*)d_ws;
    float* out = (float*)d_out;

    hipMemsetAsync(acc, 0, 4 * sizeof(float), stream);
    dim3 grid(NBX, NSTRIP, Bn);
    stereo_fused<<<grid, TPB, 0, stream>>>(left, right, dl, dr, nonocc, acc, out);
}